// Round 1
// baseline (559.947 us; speedup 1.0000x reference)
//
#include <hip/hip_runtime.h>

#define BATCH 1024
#define DMODEL 1024
#define HEADS 16

typedef short bh8 __attribute__((ext_vector_type(8)));
typedef float f4 __attribute__((ext_vector_type(4)));
typedef unsigned short u16x4 __attribute__((ext_vector_type(4)));

__device__ inline unsigned short f2b(float f) {
  union { float f; unsigned int u; } x; x.f = f;
  unsigned int r = x.u + 0x7fffu + ((x.u >> 16) & 1u);
  return (unsigned short)(r >> 16);
}

// ---- fused preprocessing: 4x transpose+cvt | x cvt | beta ----
// blocks [0,4096): transpose Wq/Wk/Wv/Wo (1024 blocks each)
// blocks [4096,5120): x fp32 -> bf16
// blocks [5120,6144): beta = sigmoid(x @ Wg)
__global__ __launch_bounds__(256)
void prep_kernel(const float* __restrict__ x,
                 const float* __restrict__ Wq, const float* __restrict__ Wk,
                 const float* __restrict__ Wv, const float* __restrict__ Wo,
                 const float* __restrict__ Wg,
                 unsigned short* __restrict__ xh, unsigned short* __restrict__ WqkvT,
                 unsigned short* __restrict__ WoT, float* __restrict__ betab) {
  __shared__ float sm[32 * 33];
  const int blk = blockIdx.x;
  if (blk < 4096) {
    const int mat = blk >> 10, id = blk & 1023;
    const float* src = (mat == 0) ? Wq : (mat == 1) ? Wk : (mat == 2) ? Wv : Wo;
    unsigned short* dst = (mat < 3) ? (WqkvT + (size_t)mat * 1024 * 1024) : WoT;
    const int c0 = (id & 31) * 32, r0 = (id >> 5) * 32;
    const int tx = threadIdx.x & 31, ty = threadIdx.x >> 5;
    #pragma unroll
    for (int i = ty; i < 32; i += 8)
      sm[i * 33 + tx] = src[(size_t)(r0 + i) * 1024 + c0 + tx];
    __syncthreads();
    #pragma unroll
    for (int i = ty; i < 32; i += 8)
      dst[(size_t)(c0 + i) * 1024 + r0 + tx] = f2b(sm[tx * 33 + i]);
  } else if (blk < 5120) {
    const int i = (blk - 4096) * 256 + threadIdx.x;
    const float4 f = ((const float4*)x)[i];
    u16x4 hv = { f2b(f.x), f2b(f.y), f2b(f.z), f2b(f.w) };
    ((u16x4*)xh)[i] = hv;
  } else {
    const int b = blk - 5120;
    float* xr = sm;
    for (int i = threadIdx.x; i < DMODEL; i += 256) xr[i] = x[(size_t)b * DMODEL + i];
    __syncthreads();
    const int wid = threadIdx.x >> 6, lane = threadIdx.x & 63;
    #pragma unroll
    for (int hh = 0; hh < 4; ++hh) {
      const int h = wid * 4 + hh;
      float p = 0.f;
      for (int i = lane; i < DMODEL; i += 64) p += xr[i] * Wg[(size_t)i * HEADS + h];
      #pragma unroll
      for (int off = 32; off > 0; off >>= 1) p += __shfl_down(p, off, 64);
      if (lane == 0) betab[b * HEADS + h] = 1.f / (1.f + __expf(-p));
    }
  }
}

// ---- bf16 MFMA GEMM: C[M][N] = A[M][K] @ Bt[N][K]^T (+bias) ----
// A, Bt bf16 row-major with K contiguous; C fp32. 256 threads, 2x2 waves.
template<int BM, int BN>
__global__ __launch_bounds__(256)
void gemm_tn(const unsigned short* __restrict__ A, const unsigned short* __restrict__ Bt,
             float* __restrict__ C, const float* __restrict__ bias, int N, int K) {
  constexpr int BK = 32;
  constexpr int LD = BK + 8;     // +16B pad: conflict-free b128 frag reads
  constexpr int TM = BM / 32;    // 16-tiles per wave in m
  constexpr int TN = BN / 32;
  __shared__ unsigned short As[BM * LD];
  __shared__ unsigned short Bs[BN * LD];
  const int tid = threadIdx.x;
  const int lane = tid & 63;
  const int wid = tid >> 6;
  const int wm = wid >> 1, wn = wid & 1;
  const int m0 = blockIdx.y * BM, n0 = blockIdx.x * BN;
  const int row16 = lane & 15;
  const int quad = lane >> 4;
  const int s_chunk = tid & 3, s_row = tid >> 2;

  f4 acc[TM][TN];
  #pragma unroll
  for (int i = 0; i < TM; ++i)
    #pragma unroll
    for (int j = 0; j < TN; ++j)
      acc[i][j] = f4{0.f, 0.f, 0.f, 0.f};

  for (int k0 = 0; k0 < K; k0 += BK) {
    #pragma unroll
    for (int p = 0; p < BM / 64; ++p) {
      int r = s_row + p * 64;
      bh8 v = *(const bh8*)(A + (size_t)(m0 + r) * K + k0 + s_chunk * 8);
      *(bh8*)(&As[r * LD + s_chunk * 8]) = v;
    }
    #pragma unroll
    for (int p = 0; p < BN / 64; ++p) {
      int r = s_row + p * 64;
      bh8 v = *(const bh8*)(Bt + (size_t)(n0 + r) * K + k0 + s_chunk * 8);
      *(bh8*)(&Bs[r * LD + s_chunk * 8]) = v;
    }
    __syncthreads();
    bh8 af[TM], bfr[TN];
    #pragma unroll
    for (int i = 0; i < TM; ++i)
      af[i] = *(const bh8*)(&As[(wm * (BM / 2) + i * 16 + row16) * LD + quad * 8]);
    #pragma unroll
    for (int j = 0; j < TN; ++j)
      bfr[j] = *(const bh8*)(&Bs[(wn * (BN / 2) + j * 16 + row16) * LD + quad * 8]);
    #pragma unroll
    for (int i = 0; i < TM; ++i)
      #pragma unroll
      for (int j = 0; j < TN; ++j)
        acc[i][j] = __builtin_amdgcn_mfma_f32_16x16x32_bf16(af[i], bfr[j], acc[i][j], 0, 0, 0);
    __syncthreads();
  }
  #pragma unroll
  for (int i = 0; i < TM; ++i) {
    #pragma unroll
    for (int j = 0; j < TN; ++j) {
      int col = n0 + wn * (BN / 2) + j * 16 + row16;
      float bv = bias ? bias[col] : 0.f;
      #pragma unroll
      for (int rg = 0; rg < 4; ++rg) {
        int row = m0 + wm * (BM / 2) + i * 16 + quad * 4 + rg;
        C[(size_t)row * N + col] = acc[i][j][rg] + bv;
      }
    }
  }
}

// ---- fast-weight delta-rule update: one block per (b,h) ----
// Fully-coalesced mapping: thread t owns float4 indices {t, t+256, t+512, t+768}
// of the 64x64 W tile, i.e. col-segment (t&15) of rows (t>>4)+16j.
// Row reduction = 16-lane shfl_xor tree (contiguous lane group within a wave).
__global__ __launch_bounds__(256)
void fastweight_kernel(const float* __restrict__ Wf, const float* __restrict__ QKV,
                       const float* __restrict__ beta, float* __restrict__ newW,
                       unsigned short* __restrict__ hiddenh) {
  const int bh = blockIdx.x;
  const int b = bh >> 4, h = bh & 15;
  const int t = threadIdx.x;
  const int seg = t & 15;          // 4-float column segment
  const int rbase = t >> 4;        // rows rbase + 16j
  const float* base = QKV + (size_t)b * 3072 + h * 64;
  const float4 qq = ((const float4*)base)[seg];
  const float4 kk = ((const float4*)(base + 1024))[seg];
  const float be = beta[bh];
  const float4* wp = (const float4*)(Wf + (size_t)bh * 4096);
  float4* op = (float4*)(newW + (size_t)bh * 4096);

  float4 w[4];
  #pragma unroll
  for (int j = 0; j < 4; ++j) w[j] = wp[t + 256 * j];     // 16B/lane, 1KB/wave-instr

  float vex[4];
  #pragma unroll
  for (int j = 0; j < 4; ++j) {
    float p = w[j].x * kk.x + w[j].y * kk.y + w[j].z * kk.z + w[j].w * kk.w;
    p += __shfl_xor(p, 1, 64);
    p += __shfl_xor(p, 2, 64);
    p += __shfl_xor(p, 4, 64);
    p += __shfl_xor(p, 8, 64);
    vex[j] = p;                    // full dot(W[r_j], k) on all 16 lanes of the group
  }
  #pragma unroll
  for (int j = 0; j < 4; ++j) {
    const int r = rbase + 16 * j;
    const float dv = be * (base[2048 + r] - vex[j]);
    w[j].x += dv * kk.x; w[j].y += dv * kk.y;
    w[j].z += dv * kk.z; w[j].w += dv * kk.w;
    op[t + 256 * j] = w[j];        // coalesced store
    float o = w[j].x * qq.x + w[j].y * qq.y + w[j].z * qq.z + w[j].w * qq.w;
    o += __shfl_xor(o, 1, 64);
    o += __shfl_xor(o, 2, 64);
    o += __shfl_xor(o, 4, 64);
    o += __shfl_xor(o, 8, 64);
    if (seg == 0) hiddenh[(size_t)b * DMODEL + h * 64 + r] = f2b(o);
  }
}

extern "C" void kernel_launch(void* const* d_in, const int* in_sizes, int n_in,
                              void* d_out, int out_size, void* d_ws, size_t ws_size,
                              hipStream_t stream) {
  const float* x  = (const float*)d_in[0];
  const float* Wf = (const float*)d_in[1];
  const float* Wq = (const float*)d_in[2];
  const float* Wk = (const float*)d_in[3];
  const float* Wv = (const float*)d_in[4];
  const float* Wg = (const float*)d_in[5];
  const float* Wo = (const float*)d_in[6];
  const float* bo = (const float*)d_in[7];
  float* out  = (float*)d_out;                       // [1024*1024]
  float* newW = out + (size_t)BATCH * DMODEL;        // [1024*16*64*64]

  // workspace layout (~24.1 MB)
  unsigned short* xh      = (unsigned short*)d_ws;                   // 2 MB
  unsigned short* WqkvT   = xh + (size_t)1024 * 1024;                // 6 MB
  unsigned short* WoT     = WqkvT + (size_t)3072 * 1024;             // 2 MB
  unsigned short* hiddenh = WoT + (size_t)1024 * 1024;               // 2 MB
  float* QKV   = (float*)(hiddenh + (size_t)1024 * 1024);            // 12 MB
  float* betab = QKV + (size_t)1024 * 3072;                          // 64 KB

  prep_kernel<<<6144, 256, 0, stream>>>(x, Wq, Wk, Wv, Wo, Wg, xh, WqkvT, WoT, betab);
  gemm_tn<64, 64><<<dim3(3072 / 64, 1024 / 64), 256, 0, stream>>>(xh, WqkvT, QKV, nullptr, 3072, 1024);
  fastweight_kernel<<<BATCH * HEADS, 256, 0, stream>>>(Wf, QKV, betab, newW, hiddenh);
  gemm_tn<64, 64><<<dim3(1024 / 64, 1024 / 64), 256, 0, stream>>>(hiddenh, WoT, out, bo, 1024, 1024);
}